// Round 12
// baseline (317.460 us; speedup 1.0000x reference)
//
#include <hip/hip_runtime.h>
#include <math.h>

#define BATCH 8
#define CH    256
#define HWPIX 4096
#define CQK_  32

typedef __bf16 bf16x8 __attribute__((ext_vector_type(8)));
typedef __bf16 bf16x4 __attribute__((ext_vector_type(4)));
typedef __bf16 bf16x2 __attribute__((ext_vector_type(2)));
typedef float  f32x4  __attribute__((ext_vector_type(4)));

#define FS_STR 68   // LDS transpose-tile row stride in bf16 (136 B: 8B-aligned)

// load a bf16x8 fragment from LDS as two 8B halves (rows only 8B-aligned)
static __device__ inline bf16x8 ld_frag(const __bf16* p) {
  bf16x4 lo = *(const bf16x4*)p;
  bf16x4 hi = *(const bf16x4*)(p + 4);
  return __builtin_shufflevector(lo, hi, 0, 1, 2, 3, 4, 5, 6, 7);
}

// load 8 consecutive fp32 from a W row, convert to bf16x8 fragment
static __device__ inline bf16x8 w_frag(const float* p) {
  const float4 a = *(const float4*)p;
  const float4 b = *(const float4*)(p + 4);
  bf16x8 r;
  r[0] = (__bf16)a.x; r[1] = (__bf16)a.y; r[2] = (__bf16)a.z; r[3] = (__bf16)a.w;
  r[4] = (__bf16)b.x; r[5] = (__bf16)b.y; r[6] = (__bf16)b.z; r[7] = (__bf16)b.w;
  return r;
}

// ---- Fused projections (R10/R11 version, kept: proj ~75 us, near its 64-us
// HBM floor). 128-pixel tiles -> 512 B DRAM chunks. grid (32, 2, 8), block 512.
__global__ __launch_bounds__(512, 4) void proj_all(
    const float* __restrict__ f1, const float* __restrict__ f2,
    const float* __restrict__ f3,
    const float* __restrict__ wq, const float* __restrict__ bq,
    const float* __restrict__ wk, const float* __restrict__ bk,
    const float* __restrict__ wv, const float* __restrict__ bv,
    __bf16* __restrict__ qT, __bf16* __restrict__ kT, __bf16* __restrict__ vv)
{
  __shared__ __align__(16) __bf16 f_s[2][128 * FS_STR];  // [px][cin] transposed
  const int t    = threadIdx.x;
  const int w    = __builtin_amdgcn_readfirstlane(t >> 6);
  const int lane = t & 63;
  const int q16  = lane & 15;
  const int quad = lane >> 4;
  const int b    = blockIdx.z;
  const int n0   = blockIdx.x * 128;
  const int mode = blockIdx.y;

  if (mode == 0) {
    const int half = t >> 8;          // 0: f1/Q staging, 1: f2/K staging
    const int th   = t & 255;
    const int px   = (th & 31) * 4;   // pixel 0..124 -> 32 thr x float4 = 512 B/ch
    const int g2   = (th >> 5) * 2;   // channel-pair base 0..14
    const int isK  = w >> 2;          // waves 0-3: Q, 4-7: K
    const int qr   = w & 3;           // 32-pixel row group

    const float* fsrc = (half ? f2 : f1) + (size_t)b * CH * HWPIX + n0;
    __bf16* fdst = f_s[half];
    const float* wmat = isK ? wk : wq;

    f32x4 acc[2][2];  // [ot][rg]
#pragma unroll
    for (int i = 0; i < 2; ++i)
#pragma unroll
      for (int j = 0; j < 2; ++j) acc[i][j] = (f32x4){0.f, 0.f, 0.f, 0.f};

    float4 rg_[8];
#define PLOAD(c0)                                                               \
    _Pragma("unroll") for (int cc = 0; cc < 4; ++cc) {                          \
      const int c = (c0) + 16 * cc + g2;                                        \
      rg_[2 * cc]     = *(const float4*)&fsrc[(size_t)c * HWPIX + px];          \
      rg_[2 * cc + 1] = *(const float4*)&fsrc[(size_t)(c + 1) * HWPIX + px];    \
    }
    PLOAD(0);
    for (int c0 = 0; c0 < CH; c0 += 64) {
      __syncthreads();  // previous iter's readers done; LDS reusable
#pragma unroll
      for (int cc = 0; cc < 4; ++cc) {
        const int c = 16 * cc + g2;
#pragma unroll
        for (int i = 0; i < 4; ++i) {
          bf16x2 pk;
          pk[0] = (__bf16)((const float*)&rg_[2 * cc])[i];
          pk[1] = (__bf16)((const float*)&rg_[2 * cc + 1])[i];
          *(bf16x2*)&fdst[(px + i) * FS_STR + c] = pk;
        }
      }
      __syncthreads();
      if (c0 < CH - 64) PLOAD(c0 + 64);  // prefetch; hides under compute
      bf16x8 af[2][2];  // [rg][kh]
#pragma unroll
      for (int rg = 0; rg < 2; ++rg)
#pragma unroll
        for (int kh = 0; kh < 2; ++kh)
          af[rg][kh] = ld_frag(&f_s[isK][(32 * qr + 16 * rg + q16) * FS_STR
                                         + 32 * kh + quad * 8]);
#pragma unroll
      for (int ot = 0; ot < 2; ++ot)
#pragma unroll
        for (int kh = 0; kh < 2; ++kh) {
          const bf16x8 wf =
              w_frag(wmat + (size_t)(16 * ot + q16) * CH + c0 + 32 * kh + quad * 8);
#pragma unroll
          for (int rg = 0; rg < 2; ++rg)
            acc[ot][rg] = __builtin_amdgcn_mfma_f32_16x16x32_bf16(
                af[rg][kh], wf, acc[ot][rg], 0, 0, 0);
        }
    }
    const float* bias = isK ? bk : bq;
    __bf16* outT = isK ? kT : qT;
    const float b0 = bias[q16], b1 = bias[16 + q16];
#pragma unroll
    for (int rg = 0; rg < 2; ++rg)
#pragma unroll
      for (int r = 0; r < 4; ++r) {
        const size_t row = (size_t)b * HWPIX + n0 + 32 * qr + 16 * rg + quad * 4 + r;
        outT[row * CQK_ + q16]      = (__bf16)(acc[0][rg][r] + b0);
        outT[row * CQK_ + 16 + q16] = (__bf16)(acc[1][rg][r] + b1);
      }
#undef PLOAD
  } else {
    // ---- V: stage 128x64 f3 c-tile once; 256 out-ch, 32 per wave.
    const int px = (t & 31) * 4;
    const int g2 = (t >> 5) * 2;   // channel-pair base 0..30
    const float* f3b = f3 + (size_t)b * CH * HWPIX + n0;

    f32x4 acc[2][8];  // [ct][nt]
#pragma unroll
    for (int ct = 0; ct < 2; ++ct)
#pragma unroll
      for (int nt = 0; nt < 8; ++nt) acc[ct][nt] = (f32x4){0.f, 0.f, 0.f, 0.f};

    float4 r_[4];
#define VLOAD(c0)                                                               \
    _Pragma("unroll") for (int cc = 0; cc < 2; ++cc) {                          \
      const int c = (c0) + 32 * cc + g2;                                        \
      r_[2 * cc]     = *(const float4*)&f3b[(size_t)c * HWPIX + px];            \
      r_[2 * cc + 1] = *(const float4*)&f3b[(size_t)(c + 1) * HWPIX + px];      \
    }
    VLOAD(0);
    for (int c0 = 0; c0 < CH; c0 += 64) {
      __syncthreads();
#pragma unroll
      for (int cc = 0; cc < 2; ++cc) {
        const int c = 32 * cc + g2;
#pragma unroll
        for (int i = 0; i < 4; ++i) {
          bf16x2 pk;
          pk[0] = (__bf16)((const float*)&r_[2 * cc])[i];
          pk[1] = (__bf16)((const float*)&r_[2 * cc + 1])[i];
          *(bf16x2*)&f_s[0][(px + i) * FS_STR + c] = pk;
        }
      }
      __syncthreads();
      if (c0 < CH - 64) VLOAD(c0 + 64);
      bf16x8 af[2][2];  // [ct][kh] : W rows (out-ch = 32w + 16ct + q16)
#pragma unroll
      for (int ct = 0; ct < 2; ++ct)
#pragma unroll
        for (int kh = 0; kh < 2; ++kh)
          af[ct][kh] = w_frag(wv + (size_t)(32 * w + 16 * ct + q16) * CH
                              + c0 + 32 * kh + quad * 8);
#pragma unroll
      for (int nt = 0; nt < 8; ++nt) {
#pragma unroll
        for (int kh = 0; kh < 2; ++kh) {
          const bf16x8 bfr =
              ld_frag(&f_s[0][(16 * nt + q16) * FS_STR + 32 * kh + quad * 8]);
#pragma unroll
          for (int ct = 0; ct < 2; ++ct)
            acc[ct][nt] = __builtin_amdgcn_mfma_f32_16x16x32_bf16(
                af[ct][kh], bfr, acc[ct][nt], 0, 0, 0);
        }
      }
    }
#pragma unroll
    for (int ct = 0; ct < 2; ++ct) {
      const float4 bi = *(const float4*)&bv[32 * w + 16 * ct + quad * 4];
#pragma unroll
      for (int nt = 0; nt < 8; ++nt) {
#pragma unroll
        for (int r = 0; r < 4; ++r) {
          const int c = 32 * w + 16 * ct + quad * 4 + r;
          vv[((size_t)b * CH + c) * HWPIX + n0 + 16 * nt + q16] =
              (__bf16)(acc[ct][nt][r] + ((const float*)&bi)[r]);
        }
      }
    }
#undef VLOAD
  }
}

// ---- WAVE-SPECIALIZED flash attention (producer/consumer, T16 idea).
// Six structural nulls (occupancy/vmcnt/barriers/conflicts/stagger) prove the
// 164-us plateau is the WITHIN-WAVE serial chain score->exp->write->read->AV,
// identical in every co-resident wave (lockstep stalls). Split the roles:
//   waves 0-3 (producers): wave qb owns q rows [16qb,+16) x ALL 64 keys/tile:
//     4 score MFMA (swapped mfma(K,Q)) + 16 expf + 4 swizzled ds_write_b64.
//   waves 4-7 (consumers): wave cc owns out-channels [64cc,+64): per tile
//     8 V loads (register double-buffered one tile ahead) + 8 P ds_read_b128
//     + 32 AV MFMA.
// Producer chain (MFMA+trans+VALU) and consumer chain (VMEM+LDS+MFMA) run in
// DIFFERENT waves on disjoint pipe mixes -> no lockstep. Same total work; the
// P swizzle algebra is byte-identical to the verified R4 layout (mt' = 2hb+mt).
// One barrier per tile: producers fill p_s[(i+1)&1] while consumers drain
// p_s[i&1]. VGPR ~150-170 -> 1 block/CU (launch_bounds 512,2); R1/R6 showed
// occupancy is weakly coupled here.
// grid 512: b = bx&7 (XCD-pinned), q-tile = bx>>3.
__global__ __launch_bounds__(512, 2) void attn_kernel(
    const __bf16* __restrict__ qT, const __bf16* __restrict__ kT,
    const __bf16* __restrict__ vv, float* __restrict__ out)
{
  __shared__ __align__(16) __bf16 p_s[2][64 * 64];  // [q][m], 128 B rows
  __shared__ float L_s[64];

  const int t    = threadIdx.x;
  const int w    = __builtin_amdgcn_readfirstlane(t >> 6);
  const int lane = t & 63;
  const int q16  = lane & 15;
  const int quad = lane >> 4;
  const int swz  = (q16 & 7) << 4;

  const int b  = blockIdx.x & 7;
  const int q0 = (blockIdx.x >> 3) * 64;

  if (w < 4) {
    // ================= PRODUCER: q rows [16*w, +16), all 64 keys/tile ======
    const int qb = w;
    const __bf16* kTb = kT + (size_t)b * HWPIX * CQK_;
    // kf[mt]: A-operand rows key = 16mt + q16, c = quad*8..+8
    const size_t koffp = (size_t)q16 * CQK_ + quad * 8;

    const bf16x8 qfrag =
        *(const bf16x8*)(qT + ((size_t)b * HWPIX + q0 + 16 * qb + q16) * CQK_ + quad * 8);

    float Lp = 0.f;  // lane: q row 16qb+q16, keys {16mt+4quad+r}
    bf16x8 kf[4];
#pragma unroll
    for (int mt = 0; mt < 4; ++mt)
      kf[mt] = *(const bf16x8*)(kTb + mt * 512 + koffp);  // tile 0

    {  // prologue: P tile 0 -> p_s[0]; prefetch kf tile 1
      f32x4 Sv[4];
#pragma unroll
      for (int mt = 0; mt < 4; ++mt)
        Sv[mt] = __builtin_amdgcn_mfma_f32_16x16x32_bf16(
            kf[mt], qfrag, (f32x4){0.f, 0.f, 0.f, 0.f}, 0, 0, 0);
      const __bf16* kb1 = kTb + 2048;
#pragma unroll
      for (int mt = 0; mt < 4; ++mt)
        kf[mt] = *(const bf16x8*)(kb1 + mt * 512 + koffp);
      char* pw = (char*)p_s[0] + (16 * qb + q16) * 128;
#pragma unroll
      for (int mt = 0; mt < 4; ++mt) {
        bf16x4 pk;
#pragma unroll
        for (int r = 0; r < 4; ++r) {
          const float e = __expf(Sv[mt][r]);  // key = 16mt + 4quad + r
          Lp += e;
          pk[r] = (__bf16)e;
        }
        *(bf16x4*)(pw + ((32 * mt + 8 * quad) ^ swz)) = pk;
      }
    }
    __syncthreads();  // (A) P0 published

    for (int i = 0; i < 64; ++i) {
      if (i < 63) {
        f32x4 Sv[4];
#pragma unroll
        for (int mt = 0; mt < 4; ++mt)
          Sv[mt] = __builtin_amdgcn_mfma_f32_16x16x32_bf16(
              kf[mt], qfrag, (f32x4){0.f, 0.f, 0.f, 0.f}, 0, 0, 0);
        const __bf16* kb2 = kTb + (size_t)((i + 2) & 63) * 2048;
#pragma unroll
        for (int mt = 0; mt < 4; ++mt)
          kf[mt] = *(const bf16x8*)(kb2 + mt * 512 + koffp);
        char* pw = (char*)p_s[(i + 1) & 1] + (16 * qb + q16) * 128;
#pragma unroll
        for (int mt = 0; mt < 4; ++mt) {
          bf16x4 pk;
#pragma unroll
          for (int r = 0; r < 4; ++r) {
            const float e = __expf(Sv[mt][r]);
            Lp += e;
            pk[r] = (__bf16)e;
          }
          *(bf16x4*)(pw + ((32 * mt + 8 * quad) ^ swz)) = pk;
        }
      }
      __syncthreads();  // per-tile barrier
    }

    // L finalize: sum over the 4 quads (same q16)
    Lp += __shfl_xor(Lp, 16);
    Lp += __shfl_xor(Lp, 32);
    if (quad == 0) L_s[16 * qb + q16] = Lp;
    __syncthreads();  // (B) L published
    // producers done
  } else {
    // ================= CONSUMER: out-channels [64*(w-4), +64) ==============
    const int cc = w - 4;
    // V base: ch = 64cc + 16ct + q16, key col = tile*64 + mh*32 + quad*8
    const __bf16* vb[4];
#pragma unroll
    for (int ct = 0; ct < 4; ++ct)
      vb[ct] = vv + ((size_t)b * CH + 64 * cc + 16 * ct + q16) * HWPIX + quad * 8;

    f32x4 oacc[4][4];
#pragma unroll
    for (int i = 0; i < 4; ++i)
#pragma unroll
      for (int j = 0; j < 4; ++j)
        oacc[i][j] = (f32x4){0.f, 0.f, 0.f, 0.f};

    bf16x8 vfA[4][2], vfB[4][2];
#pragma unroll
    for (int ct = 0; ct < 4; ++ct)
#pragma unroll
      for (int mh = 0; mh < 2; ++mh)
        vfA[ct][mh] = *(const bf16x8*)(vb[ct] + mh * 32);  // tile 0
    __syncthreads();  // (A) P0 ready

#define CITER(I, VCUR, VNXT)                                                    \
    {                                                                           \
      const int i_ = (I);                                                       \
      if (i_ < 63) {  /* prefetch V tile i+1 (landed by next iter's MFMAs) */   \
        const size_t vt = (size_t)(i_ + 1) * 64;                                \
        _Pragma("unroll") for (int ct = 0; ct < 4; ++ct)                        \
          _Pragma("unroll") for (int mh = 0; mh < 2; ++mh)                      \
            VNXT[ct][mh] = *(const bf16x8*)(vb[ct] + vt + mh * 32);             \
      }                                                                         \
      const char* pb = (const char*)p_s[i_ & 1];                                \
      _Pragma("unroll") for (int mh = 0; mh < 2; ++mh) {                        \
        bf16x8 pf[4];                                                           \
        _Pragma("unroll") for (int nt = 0; nt < 4; ++nt)                        \
          pf[nt] = *(const bf16x8*)(pb + (16 * nt + q16) * 128                  \
                                    + ((64 * mh + 16 * quad) ^ swz));           \
        _Pragma("unroll") for (int ct = 0; ct < 4; ++ct)                        \
          _Pragma("unroll") for (int nt = 0; nt < 4; ++nt)                      \
            oacc[ct][nt] = __builtin_amdgcn_mfma_f32_16x16x32_bf16(             \
                VCUR[ct][mh], pf[nt], oacc[ct][nt], 0, 0, 0);                   \
      }                                                                         \
      __syncthreads();                                                          \
    }

    for (int i = 0; i < 64; i += 2) {
      CITER(i, vfA, vfB);
      CITER(i + 1, vfB, vfA);
    }
#undef CITER

    __syncthreads();  // (B) L ready

    float rinv[4];
#pragma unroll
    for (int nt = 0; nt < 4; ++nt) rinv[nt] = 1.0f / L_s[16 * nt + q16];

    float* ob = out + ((size_t)b * CH + 64 * cc) * HWPIX + q0;
#pragma unroll
    for (int ct = 0; ct < 4; ++ct)
#pragma unroll
      for (int r = 0; r < 4; ++r)
#pragma unroll
        for (int nt = 0; nt < 4; ++nt)
          ob[(size_t)(16 * ct + quad * 4 + r) * HWPIX + 16 * nt + q16] =
              oacc[ct][nt][r] * rinv[nt];
  }
}

extern "C" void kernel_launch(void* const* d_in, const int* in_sizes, int n_in,
                              void* d_out, int out_size, void* d_ws, size_t ws_size,
                              hipStream_t stream)
{
  const float* f1 = (const float*)d_in[0];
  const float* f2 = (const float*)d_in[1];
  const float* f3 = (const float*)d_in[2];
  const float* wq = (const float*)d_in[3];
  const float* bq = (const float*)d_in[4];
  const float* wk = (const float*)d_in[5];
  const float* bk = (const float*)d_in[6];
  const float* wv = (const float*)d_in[7];
  const float* bv = (const float*)d_in[8];
  float* outp = (float*)d_out;

  // workspace: qT [8][4096][32] | kT [8][4096][32] | v [8][256][4096]  (bf16, 20 MB)
  __bf16* qTw = (__bf16*)d_ws;
  __bf16* kTw = qTw + (size_t)BATCH * HWPIX * CQK_;
  __bf16* vw  = kTw + (size_t)BATCH * HWPIX * CQK_;

  proj_all<<<dim3(32, 2, 8), 512, 0, stream>>>(f1, f2, f3, wq, bq, wk, bk, wv, bv,
                                               qTw, kTw, vw);
  attn_kernel<<<dim3(512), 512, 0, stream>>>(qTw, kTw, vw, outp);
}